// Round 5
// baseline (1710.363 us; speedup 1.0000x reference)
//
#include <hip/hip_runtime.h>

typedef unsigned short ushort_t;
typedef __attribute__((ext_vector_type(8))) short bf16x8;
typedef __attribute__((ext_vector_type(4))) float f32x4;
typedef __attribute__((ext_vector_type(4))) unsigned int u32x4;

#define DEV __device__ __forceinline__
#define MFMA16 __builtin_amdgcn_mfma_f32_16x16x32_bf16

// plane strides (elements)
#define PS_H    8388608UL   // 4096*2048
#define PS_WQKV 6291456UL   // 3072*2048
#define PS_WO   4194304UL   // 2048*2048
#define PS_Q    8388608UL   // 2*16*2048*128
#define PS_KV   2097152UL   // 2*4*2048*128
#define PS_AO   8388608UL   // 4096*2048

DEV ushort_t f2bf(float f) {
  unsigned u = __builtin_bit_cast(unsigned, f);
  u += 0x7fffu + ((u >> 16) & 1u);
  return (ushort_t)(u >> 16);
}
DEV float bf2f(ushort_t u) {
  unsigned v = ((unsigned)u) << 16;
  return __builtin_bit_cast(float, v);
}
DEV void splitbf(float v, ushort_t& hi, ushort_t& lo) {
  hi = f2bf(v);
  lo = f2bf(v - bf2f(hi));
}

DEV void gload16(const ushort_t* g, ushort_t* l) {
  __builtin_amdgcn_global_load_lds(
      (const __attribute__((address_space(1))) unsigned int*)g,
      (__attribute__((address_space(3))) unsigned int*)l, 16, 0, 0);
}

// ---------------- generic 128x128 bf16 GEMM mainloop (m97 structure) -------
DEV void gemm_loop(int K,
                   const ushort_t* __restrict__ a0, const ushort_t* __restrict__ a1,
                   const ushort_t* __restrict__ b0, const ushort_t* __restrict__ b1,
                   ushort_t* ldsA, ushort_t* ldsB, ushort_t* ldsAw, ushort_t* ldsBw,
                   const int (&ao_)[4], const int (&bo_)[4], f32x4 (&acc)[4][4])
{
  for (int k0 = 0; k0 < K; k0 += 32) {
    __syncthreads();
    gload16(a0 + k0, ldsAw);
    gload16(a1 + k0, ldsAw + 2048);
    gload16(b0 + k0, ldsBw);
    gload16(b1 + k0, ldsBw + 2048);
    __syncthreads();
    bf16x8 af[4], bv[4];
#pragma unroll
    for (int i = 0; i < 4; i++) af[i] = *(const bf16x8*)(ldsA + ao_[i]);
#pragma unroll
    for (int i = 0; i < 4; i++) bv[i] = *(const bf16x8*)(ldsB + bo_[i]);
#pragma unroll
    for (int m = 0; m < 4; m++)
#pragma unroll
      for (int n = 0; n < 4; n++)
        acc[m][n] = MFMA16(af[m], bv[n], acc[m][n], 0, 0, 0);
  }
}

#define GEMM_PROLOGUE()                                                        \
  __shared__ __align__(16) ushort_t ldsA[4096];                                \
  __shared__ __align__(16) ushort_t ldsB[4096];                                \
  int t = threadIdx.x, lane = t & 63, w = t >> 6;                              \
  int rS = t >> 2, cS = (t & 3) * 8;                                           \
  int wm = w >> 1, wn = w & 1;                                                 \
  int q15 = lane & 15, g = lane >> 4;                                          \
  int ao_[4], bo_[4];                                                          \
  _Pragma("unroll")                                                            \
  for (int i = 0; i < 4; i++) {                                                \
    ao_[i] = (wm * 64 + i * 16 + q15) * 32 + g * 8;                            \
    bo_[i] = (wn * 64 + i * 16 + q15) * 32 + g * 8;                            \
  }                                                                            \
  f32x4 acc[4][4];                                                             \
  _Pragma("unroll")                                                            \
  for (int m_ = 0; m_ < 4; m_++)                                               \
    _Pragma("unroll")                                                          \
    for (int n_ = 0; n_ < 4; n_++) acc[m_][n_] = f32x4{0.f, 0.f, 0.f, 0.f};

// ---------------- small utility kernels ------------------------------------
__global__ void k_zero(int* cnt, float* psum) {
  int t = threadIdx.x;
  if (t < 8) { cnt[t] = 0; psum[t] = 0.f; }
}

__global__ __launch_bounds__(256) void k_ropetab(float* __restrict__ cosT,
                                                 float* __restrict__ sinT) {
  int idx = blockIdx.x * 256 + threadIdx.x;  // 2048*64
  int pos = idx >> 6, i = idx & 63;
  double inv = pow(10000.0, -(double)i / 64.0);
  double ang = (double)pos * inv;
  cosT[idx] = (float)cos(ang);
  sinT[idx] = (float)sin(ang);
}

// single-plane: dst[(dstOff+n)][k] (ld=R) = bf16(src[k][n]); src is R x C
__global__ __launch_bounds__(256) void k_transcvt(const float* __restrict__ src,
    ushort_t* __restrict__ dst, int R, int C, int dstOff, long srcZ, long dstZ)
{
  __shared__ float tl[32][33];
  src += (size_t)blockIdx.z * srcZ;
  dst += (size_t)blockIdx.z * dstZ;
  int k0 = blockIdx.x * 32, n0 = blockIdx.y * 32;
  int tx = threadIdx.x & 31, ty = threadIdx.x >> 5;
#pragma unroll
  for (int j = 0; j < 4; j++)
    tl[ty + j * 8][tx] = src[(size_t)(k0 + ty + j * 8) * C + n0 + tx];
  __syncthreads();
#pragma unroll
  for (int j = 0; j < 4; j++) {
    int n = ty + j * 8;
    dst[(size_t)(dstOff + n0 + n) * R + k0 + tx] = f2bf(tl[tx][n]);
  }
}

// split hi/lo planes: dst[(dstOff+n)][k] = hi, dst[PS + ...] = lo
__global__ __launch_bounds__(256) void k_transcvt2(const float* __restrict__ src,
    ushort_t* __restrict__ dst, int R, int C, int dstOff, size_t PS)
{
  __shared__ float tl[32][33];
  int k0 = blockIdx.x * 32, n0 = blockIdx.y * 32;
  int tx = threadIdx.x & 31, ty = threadIdx.x >> 5;
#pragma unroll
  for (int j = 0; j < 4; j++)
    tl[ty + j * 8][tx] = src[(size_t)(k0 + ty + j * 8) * C + n0 + tx];
  __syncthreads();
#pragma unroll
  for (int j = 0; j < 4; j++) {
    int n = ty + j * 8;
    ushort_t hi, lo;
    splitbf(tl[tx][n], hi, lo);
    size_t idx = (size_t)(dstOff + n0 + n) * R + k0 + tx;
    dst[idx] = hi;
    dst[PS + idx] = lo;
  }
}

// interleaved w1/w3 transpose: dst[e][2c+s][k] = (s ? w3 : w1)[e][k][c]
__global__ __launch_bounds__(256) void k_transcvt13(const float* __restrict__ w1,
    const float* __restrict__ w3, ushort_t* __restrict__ dst)
{
  __shared__ float t1[32][33], t3[32][33];
  int e = blockIdx.z;
  const float* s1 = w1 + (size_t)e * 2048 * 1024;
  const float* s3 = w3 + (size_t)e * 2048 * 1024;
  ushort_t* d = dst + (size_t)e * 2048 * 2048;
  int k0 = blockIdx.x * 32, c0 = blockIdx.y * 32;
  int tx = threadIdx.x & 31, ty = threadIdx.x >> 5;
#pragma unroll
  for (int j = 0; j < 4; j++) {
    t1[ty + j * 8][tx] = s1[(size_t)(k0 + ty + j * 8) * 1024 + c0 + tx];
    t3[ty + j * 8][tx] = s3[(size_t)(k0 + ty + j * 8) * 1024 + c0 + tx];
  }
  __syncthreads();
#pragma unroll
  for (int j = 0; j < 4; j++) {
    int c = ty + j * 8;
    d[(size_t)(2 * (c0 + c)) * 2048 + k0 + tx] = f2bf(t1[tx][c]);
    d[(size_t)(2 * (c0 + c) + 1) * 2048 + k0 + tx] = f2bf(t3[tx][c]);
  }
}

// single-plane rmsnorm (MoE input)
__global__ __launch_bounds__(256) void k_rmsnorm(const float* __restrict__ x,
    const float* __restrict__ wgt, ushort_t* __restrict__ out)
{
  int row = blockIdx.x;
  int t = threadIdx.x;
  const float* xr = x + (size_t)row * 2048;
  float4 a = *(const float4*)(xr + t * 8);
  float4 b = *(const float4*)(xr + t * 8 + 4);
  float ss = a.x * a.x + a.y * a.y + a.z * a.z + a.w * a.w +
             b.x * b.x + b.y * b.y + b.z * b.z + b.w * b.w;
#pragma unroll
  for (int o = 32; o; o >>= 1) ss += __shfl_xor(ss, o, 64);
  __shared__ float red[4];
  if ((t & 63) == 0) red[t >> 6] = ss;
  __syncthreads();
  float tot = red[0] + red[1] + red[2] + red[3];
  float r = 1.0f / sqrtf(tot * (1.0f / 2048.0f) + 1e-5f);
  float4 wa = *(const float4*)(wgt + t * 8);
  float4 wb = *(const float4*)(wgt + t * 8 + 4);
  unsigned o0 = (unsigned)f2bf(a.x * r * wa.x) | ((unsigned)f2bf(a.y * r * wa.y) << 16);
  unsigned o1 = (unsigned)f2bf(a.z * r * wa.z) | ((unsigned)f2bf(a.w * r * wa.w) << 16);
  unsigned o2 = (unsigned)f2bf(b.x * r * wb.x) | ((unsigned)f2bf(b.y * r * wb.y) << 16);
  unsigned o3 = (unsigned)f2bf(b.z * r * wb.z) | ((unsigned)f2bf(b.w * r * wb.w) << 16);
  u32x4 ov = {o0, o1, o2, o3};
  *(u32x4*)(out + (size_t)row * 2048 + t * 8) = ov;
}

// split-plane rmsnorm (attention input)
__global__ __launch_bounds__(256) void k_rmsnorm2(const float* __restrict__ x,
    const float* __restrict__ wgt, ushort_t* __restrict__ out)
{
  int row = blockIdx.x;
  int t = threadIdx.x;
  const float* xr = x + (size_t)row * 2048;
  float4 a = *(const float4*)(xr + t * 8);
  float4 b = *(const float4*)(xr + t * 8 + 4);
  float ss = a.x * a.x + a.y * a.y + a.z * a.z + a.w * a.w +
             b.x * b.x + b.y * b.y + b.z * b.z + b.w * b.w;
#pragma unroll
  for (int o = 32; o; o >>= 1) ss += __shfl_xor(ss, o, 64);
  __shared__ float red[4];
  if ((t & 63) == 0) red[t >> 6] = ss;
  __syncthreads();
  float tot = red[0] + red[1] + red[2] + red[3];
  float r = 1.0f / sqrtf(tot * (1.0f / 2048.0f) + 1e-5f);
  float4 wa = *(const float4*)(wgt + t * 8);
  float4 wb = *(const float4*)(wgt + t * 8 + 4);
  float v[8] = {a.x * r * wa.x, a.y * r * wa.y, a.z * r * wa.z, a.w * r * wa.w,
                b.x * r * wb.x, b.y * r * wb.y, b.z * r * wb.z, b.w * r * wb.w};
  ushort_t hi[8], lo[8];
#pragma unroll
  for (int j = 0; j < 8; j++) splitbf(v[j], hi[j], lo[j]);
  u32x4 hv = {(unsigned)hi[0] | ((unsigned)hi[1] << 16), (unsigned)hi[2] | ((unsigned)hi[3] << 16),
              (unsigned)hi[4] | ((unsigned)hi[5] << 16), (unsigned)hi[6] | ((unsigned)hi[7] << 16)};
  u32x4 lv = {(unsigned)lo[0] | ((unsigned)lo[1] << 16), (unsigned)lo[2] | ((unsigned)lo[3] << 16),
              (unsigned)lo[4] | ((unsigned)lo[5] << 16), (unsigned)lo[6] | ((unsigned)lo[7] << 16)};
  size_t idx = (size_t)row * 2048 + t * 8;
  *(u32x4*)(out + idx) = hv;
  *(u32x4*)(out + PS_H + idx) = lv;
}

// ---------------- QKV GEMM (split 3x) with fused RoPE + layout split -------
__global__ __launch_bounds__(256) void k_gemm_qkv(
    const ushort_t* __restrict__ hbf, const ushort_t* __restrict__ wt,
    const float* __restrict__ cosT, const float* __restrict__ sinT,
    ushort_t* __restrict__ qb, ushort_t* __restrict__ kb, ushort_t* __restrict__ vtb)
{
  GEMM_PROLOGUE();
  int n0 = blockIdx.x * 128, m0 = blockIdx.y * 128;
  const ushort_t* ah0 = hbf + (size_t)(m0 + rS) * 2048 + cS;
  const ushort_t* ah1 = ah0 + (size_t)64 * 2048;
  const ushort_t* al0 = ah0 + PS_H;
  const ushort_t* al1 = ah1 + PS_H;
  const ushort_t* bh0 = wt + (size_t)(n0 + rS) * 2048 + cS;
  const ushort_t* bh1 = bh0 + (size_t)64 * 2048;
  const ushort_t* bl0 = bh0 + PS_WQKV;
  const ushort_t* bl1 = bh1 + PS_WQKV;
  gemm_loop(2048, ah0, ah1, bh0, bh1, ldsA, ldsB, ldsA + w * 512, ldsB + w * 512, ao_, bo_, acc);
  gemm_loop(2048, ah0, ah1, bl0, bl1, ldsA, ldsB, ldsA + w * 512, ldsB + w * 512, ao_, bo_, acc);
  gemm_loop(2048, al0, al1, bh0, bh1, ldsA, ldsB, ldsA + w * 512, ldsB + w * 512, ao_, bo_, acc);
#pragma unroll
  for (int fn = 0; fn < 4; fn++) {
    int col = n0 + wn * 64 + fn * 16 + q15;
#pragma unroll
    for (int fm = 0; fm < 4; fm++) {
      int row0 = m0 + wm * 64 + fm * 16 + g * 4;
      f32x4 v = acc[fm][fn];
      if (col < 2560) {  // q or k: RoPE
        int fi = (col & 127) >> 1;
        int even = !(col & 1);
#pragma unroll
        for (int r = 0; r < 4; r++) {
          int rowg = row0 + r;
          int bb = rowg >> 11, pos = rowg & 2047;
          float val = v[r];
          float prt = __shfl_xor(val, 1, 64);
          float c = cosT[pos * 64 + fi], s = sinT[pos * 64 + fi];
          float ov = even ? (val * c - prt * s) : (prt * s + val * c);
          ushort_t hi, lo;
          splitbf(ov, hi, lo);
          if (col < 2048) {
            int hh = col >> 7, d = col & 127;
            size_t idx = (((size_t)bb * 16 + hh) * 2048 + pos) * 128 + d;
            qb[idx] = hi;
            qb[PS_Q + idx] = lo;
          } else {
            int kv = (col - 2048) >> 7, d = col & 127;
            size_t idx = (((size_t)bb * 4 + kv) * 2048 + pos) * 128 + d;
            kb[idx] = hi;
            kb[PS_KV + idx] = lo;
          }
        }
      } else {  // v: transposed store [b][kvh][d][pos]
        int kv = (col - 2560) >> 7, d = col & 127;
#pragma unroll
        for (int r = 0; r < 4; r++) {
          int rowg = row0 + r;
          int bb = rowg >> 11, pos = rowg & 2047;
          ushort_t hi, lo;
          splitbf(v[r], hi, lo);
          size_t idx = (((size_t)bb * 4 + kv) * 128 + d) * 2048 + pos;
          vtb[idx] = hi;
          vtb[PS_KV + idx] = lo;
        }
      }
    }
  }
}

// ---------------- flash attention (split 3x), 1 wave per 16 q rows ---------
__global__ __launch_bounds__(64) void k_attn(
    const ushort_t* __restrict__ qb, const ushort_t* __restrict__ kb,
    const ushort_t* __restrict__ vtb, ushort_t* __restrict__ aob)
{
  int lane = threadIdx.x;
  int qt = blockIdx.x, h = blockIdx.y, b = blockIdx.z;
  int kvh = h >> 2;
  int q0 = qt * 16;
  int q15 = lane & 15, g = lane >> 4;
  const ushort_t* qbase = qb + ((size_t)b * 16 + h) * 2048 * 128;
  const ushort_t* kbase = kb + ((size_t)b * 4 + kvh) * 2048 * 128;
  const ushort_t* vbase = vtb + ((size_t)b * 4 + kvh) * 128 * 2048;
  bf16x8 qh[4], ql[4];
#pragma unroll
  for (int dk = 0; dk < 4; dk++) {
    size_t qoff = (size_t)(q0 + q15) * 128 + dk * 32 + g * 8;
    qh[dk] = *(const bf16x8*)(qbase + qoff);
    ql[dk] = *(const bf16x8*)(qbase + PS_Q + qoff);
  }
  f32x4 acc[8];
#pragma unroll
  for (int i = 0; i < 8; i++) acc[i] = f32x4{0.f, 0.f, 0.f, 0.f};
  float m = -1e30f, l = 0.f;
  const float c1 = 0.12751744f;  // (1/sqrt(128)) * log2(e)
  int nkv = q0 + 16;
  for (int kv0 = 0; kv0 < nkv; kv0 += 32) {
    f32x4 sf[2];
#pragma unroll
    for (int sub = 0; sub < 2; sub++) {
      int kvs = kv0 + sub * 16;
      f32x4 s = f32x4{0.f, 0.f, 0.f, 0.f};
#pragma unroll
      for (int dk = 0; dk < 4; dk++) {
        size_t koff = (size_t)(kvs + q15) * 128 + dk * 32 + g * 8;
        bf16x8 kh = *(const bf16x8*)(kbase + koff);
        bf16x8 kl = *(const bf16x8*)(kbase + PS_KV + koff);
        s = MFMA16(kh, qh[dk], s, 0, 0, 0);
        s = MFMA16(kh, ql[dk], s, 0, 0, 0);
        s = MFMA16(kl, qh[dk], s, 0, 0, 0);
      }
      sf[sub] = s;
    }
    float tmax = -1e30f;
#pragma unroll
    for (int sub = 0; sub < 2; sub++)
#pragma unroll
      for (int r = 0; r < 4; r++) {
        float sv = sf[sub][r] * c1;
        int kva = kv0 + sub * 16 + g * 4 + r;
        sv = (kva > q0 + q15) ? -1e30f : sv;
        sf[sub][r] = sv;
        tmax = fmaxf(tmax, sv);
      }
    tmax = fmaxf(tmax, __shfl_xor(tmax, 16, 64));
    tmax = fmaxf(tmax, __shfl_xor(tmax, 32, 64));
    float mnew = fmaxf(m, tmax);
    float scl = __builtin_amdgcn_exp2f(m - mnew);
    m = mnew;
    l *= scl;
#pragma unroll
    for (int i = 0; i < 8; i++) acc[i] *= scl;
    unsigned pkh[2][2], pkl[2][2];
#pragma unroll
    for (int sub = 0; sub < 2; sub++) {
      float p[4];
#pragma unroll
      for (int r = 0; r < 4; r++) {
        p[r] = __builtin_amdgcn_exp2f(sf[sub][r] - m);
        l += p[r];
      }
      ushort_t hi[4], lo[4];
#pragma unroll
      for (int r = 0; r < 4; r++) splitbf(p[r], hi[r], lo[r]);
      pkh[sub][0] = (unsigned)hi[0] | ((unsigned)hi[1] << 16);
      pkh[sub][1] = (unsigned)hi[2] | ((unsigned)hi[3] << 16);
      pkl[sub][0] = (unsigned)lo[0] | ((unsigned)lo[1] << 16);
      pkl[sub][1] = (unsigned)lo[2] | ((unsigned)lo[3] << 16);
    }
    // reshape P (D layout) -> B-operand layout via shuffles (hi & lo sets)
    int src0 = q15 + 16 * ((2 * g) & 3);
    int src1 = q15 + 16 * ((2 * g + 1) & 3);
    unsigned h00 = __shfl(pkh[0][0], src0, 64);
    unsigned h01 = __shfl(pkh[0][1], src0, 64);
    unsigned h02 = __shfl(pkh[0][0], src1, 64);
    unsigned h03 = __shfl(pkh[0][1], src1, 64);
    unsigned h10 = __shfl(pkh[1][0], src0, 64);
    unsigned h11 = __shfl(pkh[1][1], src0, 64);
    unsigned h12 = __shfl(pkh[1][0], src1, 64);
    unsigned h13 = __shfl(pkh[1][1], src1, 64);
    unsigned l00 = __shfl(pkl[0][0], src0, 64);
    unsigned l01 = __shfl(pkl[0][1], src0, 64);
    unsigned l02 = __shfl(pkl[0][0], src1, 64);
    unsigned l03 = __shfl(pkl[0][1], src1, 64);
    unsigned l10 = __shfl(pkl[1][0], src0, 64);
    unsigned l11 = __shfl(pkl[1][1], src0, 64);
    unsigned l12 = __shfl(pkl[1][0], src1, 64);
    unsigned l13 = __shfl(pkl[1][1], src1, 64);
    bool hiG = g >= 2;
    u32x4 pvh = {hiG ? h10 : h00, hiG ? h11 : h01, hiG ? h12 : h02, hiG ? h13 : h03};
    u32x4 pvl = {hiG ? l10 : l00, hiG ? l11 : l01, hiG ? l12 : l02, hiG ? l13 : l03};
    bf16x8 pbh = __builtin_bit_cast(bf16x8, pvh);
    bf16x8 pbl = __builtin_bit_cast(bf16x8, pvl);
#pragma unroll
    for (int db = 0; db < 8; db++) {
      size_t voff = (size_t)(db * 16 + q15) * 2048 + kv0 + g * 8;
      bf16x8 vh = *(const bf16x8*)(vbase + voff);
      bf16x8 vl = *(const bf16x8*)(vbase + PS_KV + voff);
      acc[db] = MFMA16(vh, pbh, acc[db], 0, 0, 0);
      acc[db] = MFMA16(vh, pbl, acc[db], 0, 0, 0);
      acc[db] = MFMA16(vl, pbh, acc[db], 0, 0, 0);
    }
  }
  l += __shfl_xor(l, 16, 64);
  l += __shfl_xor(l, 32, 64);
  float inv = 1.0f / l;
  size_t tok = (size_t)b * 2048 + q0 + q15;
#pragma unroll
  for (int db = 0; db < 8; db++) {
    ushort_t hi[4], lo[4];
#pragma unroll
    for (int r = 0; r < 4; r++) splitbf(acc[db][r] * inv, hi[r], lo[r]);
    uint2 hv = {(unsigned)hi[0] | ((unsigned)hi[1] << 16), (unsigned)hi[2] | ((unsigned)hi[3] << 16)};
    uint2 lv = {(unsigned)lo[0] | ((unsigned)lo[1] << 16), (unsigned)lo[2] | ((unsigned)lo[3] << 16)};
    size_t idx = tok * 2048 + h * 128 + db * 16 + g * 4;
    *(uint2*)(aob + idx) = hv;
    *(uint2*)(aob + PS_AO + idx) = lv;
  }
}

// ---------------- O-proj GEMM (split 3x) + residual ------------------------
__global__ __launch_bounds__(256) void k_gemm_o(
    const ushort_t* __restrict__ aob, const ushort_t* __restrict__ wot,
    const float* __restrict__ xin, float* __restrict__ out)
{
  GEMM_PROLOGUE();
  int n0 = blockIdx.x * 128, m0 = blockIdx.y * 128;
  const ushort_t* ah0 = aob + (size_t)(m0 + rS) * 2048 + cS;
  const ushort_t* ah1 = ah0 + (size_t)64 * 2048;
  const ushort_t* al0 = ah0 + PS_AO;
  const ushort_t* al1 = ah1 + PS_AO;
  const ushort_t* bh0 = wot + (size_t)(n0 + rS) * 2048 + cS;
  const ushort_t* bh1 = bh0 + (size_t)64 * 2048;
  const ushort_t* bl0 = bh0 + PS_WO;
  const ushort_t* bl1 = bh1 + PS_WO;
  gemm_loop(2048, ah0, ah1, bh0, bh1, ldsA, ldsB, ldsA + w * 512, ldsB + w * 512, ao_, bo_, acc);
  gemm_loop(2048, ah0, ah1, bl0, bl1, ldsA, ldsB, ldsA + w * 512, ldsB + w * 512, ao_, bo_, acc);
  gemm_loop(2048, al0, al1, bh0, bh1, ldsA, ldsB, ldsA + w * 512, ldsB + w * 512, ao_, bo_, acc);
#pragma unroll
  for (int fn = 0; fn < 4; fn++) {
    int col = n0 + wn * 64 + fn * 16 + q15;
#pragma unroll
    for (int fm = 0; fm < 4; fm++) {
      int row0 = m0 + wm * 64 + fm * 16 + g * 4;
      f32x4 v = acc[fm][fn];
#pragma unroll
      for (int r = 0; r < 4; r++) {
        size_t idx = (size_t)(row0 + r) * 2048 + col;
        out[idx] = v[r] + xin[idx];
      }
    }
  }
}

// ---------------- gate: f32 logits, softmax, top-2, aux stats --------------
__global__ __launch_bounds__(256) void k_gate(const float* __restrict__ x2,
    const float* __restrict__ gw, const float* __restrict__ mnw,
    int* __restrict__ top_idx, float* __restrict__ top_w,
    int* __restrict__ cnt, float* __restrict__ psum)
{
  __shared__ float sps[8];
  __shared__ int scnt[8];
  int t = threadIdx.x;
  if (t < 8) { sps[t] = 0.f; scnt[t] = 0; }
  __syncthreads();
  int wv = t >> 6, lane = t & 63;
  int tok = blockIdx.x * 4 + wv;
  const float* xr = x2 + (size_t)tok * 2048;
  float p[8];
#pragma unroll
  for (int e = 0; e < 8; e++) p[e] = 0.f;
  float ss = 0.f;
  for (int i = 0; i < 32; i++) {
    int d = i * 64 + lane;
    float xd = xr[d];
    ss += xd * xd;
    float tt = xd * mnw[d];
    const float4* g4 = (const float4*)(gw + (size_t)d * 8);
    float4 ga = g4[0], gb = g4[1];
    p[0] += tt * ga.x; p[1] += tt * ga.y; p[2] += tt * ga.z; p[3] += tt * ga.w;
    p[4] += tt * gb.x; p[5] += tt * gb.y; p[6] += tt * gb.z; p[7] += tt * gb.w;
  }
#pragma unroll
  for (int o = 32; o; o >>= 1) {
    ss += __shfl_xor(ss, o, 64);
#pragma unroll
    for (int e = 0; e < 8; e++) p[e] += __shfl_xor(p[e], o, 64);
  }
  if (lane == 0) {
    float r = 1.0f / sqrtf(ss * (1.0f / 2048.0f) + 1e-5f);
    float mx = -1e30f;
#pragma unroll
    for (int e = 0; e < 8; e++) { p[e] *= r; mx = fmaxf(mx, p[e]); }
    float S = 0.f;
#pragma unroll
    for (int e = 0; e < 8; e++) { p[e] = __expf(p[e] - mx); S += p[e]; }
    float is = 1.0f / S;
    int i0 = 0, i1 = 0;
    float s0 = -1.f, s1 = -2.f;
#pragma unroll
    for (int e = 0; e < 8; e++) {
      float se = p[e] * is;
      p[e] = se;
      if (se > s0) { s1 = s0; i1 = i0; s0 = se; i0 = e; }
      else if (se > s1) { s1 = se; i1 = e; }
    }
    float dn = 1.0f / (s0 + s1);
    top_idx[tok * 2] = i0; top_idx[tok * 2 + 1] = i1;
    top_w[tok * 2] = s0 * dn; top_w[tok * 2 + 1] = s1 * dn;
    atomicAdd(&scnt[i0], 1); atomicAdd(&scnt[i1], 1);
#pragma unroll
    for (int e = 0; e < 8; e++) atomicAdd(&sps[e], p[e]);
  }
  __syncthreads();
  if (t < 8) { atomicAdd(&cnt[t], scnt[t]); atomicAdd(&psum[t], sps[t]); }
}

__global__ void k_scan(const int* __restrict__ cnt, const float* __restrict__ psum,
                       int* __restrict__ offs, int* __restrict__ cur,
                       float* __restrict__ aux_out)
{
  if (threadIdx.x == 0) {
    int o = 0;
    float aux = 0.f;
    for (int e = 0; e < 8; e++) {
      offs[e] = o; cur[e] = o; o += cnt[e];
      aux += ((float)cnt[e] / 4096.f) * (psum[e] / 4096.f);
    }
    offs[8] = o;
    aux_out[0] = 0.01f * 8.f * aux;
  }
}

__global__ __launch_bounds__(256) void k_scatter(const int* __restrict__ top_idx,
    const float* __restrict__ top_w, int* __restrict__ cur,
    int* __restrict__ tok_of_slot, float* __restrict__ slot_w)
{
  int tk = blockIdx.x * 256 + threadIdx.x;
  if (tk < 4096) {
#pragma unroll
    for (int k = 0; k < 2; k++) {
      int e = top_idx[tk * 2 + k];
      int slot = atomicAdd(&cur[e], 1);
      tok_of_slot[slot] = tk;
      slot_w[slot] = top_w[tk * 2 + k];
    }
  }
}

// ---------------- MoE GEMM1: gather rows, fused SiLU*u ---------------------
__global__ __launch_bounds__(256) void k_gemm1(
    const ushort_t* __restrict__ hmb, const ushort_t* __restrict__ w13t,
    const int* __restrict__ tok_of_slot, const int* __restrict__ offs,
    ushort_t* __restrict__ yb)
{
  int e = blockIdx.y >> 5, mt = blockIdx.y & 31;
  int sege = offs[e + 1];
  int m0 = offs[e] + mt * 128;
  if (m0 >= sege) return;
  GEMM_PROLOGUE();
  int n0 = blockIdx.x * 128;
  int gr0 = m0 + rS; if (gr0 > 8191) gr0 = 8191;
  int gr1 = m0 + rS + 64; if (gr1 > 8191) gr1 = 8191;
  const ushort_t* a0 = hmb + (size_t)tok_of_slot[gr0] * 2048 + cS;
  const ushort_t* a1 = hmb + (size_t)tok_of_slot[gr1] * 2048 + cS;
  const ushort_t* b0 = w13t + (size_t)e * 2048 * 2048 + (size_t)(n0 + rS) * 2048 + cS;
  const ushort_t* b1 = b0 + (size_t)64 * 2048;
  gemm_loop(2048, a0, a1, b0, b1, ldsA, ldsB, ldsA + w * 512, ldsB + w * 512,
            ao_, bo_, acc);
#pragma unroll
  for (int fn = 0; fn < 4; fn++) {
    int col = n0 + wn * 64 + fn * 16 + q15;
#pragma unroll
    for (int fm = 0; fm < 4; fm++) {
      int row0 = m0 + wm * 64 + fm * 16 + g * 4;
      f32x4 v = acc[fm][fn];
#pragma unroll
      for (int r = 0; r < 4; r++) {
        float val = v[r];
        float prt = __shfl_xor(val, 1, 64);  // partner col (u for even lanes)
        int rowg = row0 + r;
        if (!(col & 1) && rowg < sege) {
          float sg = val / (1.f + __expf(-val));
          yb[(size_t)rowg * 1024 + (col >> 1)] = f2bf(sg * prt);
        }
      }
    }
  }
}

// ---------------- MoE GEMM2: scatter-add combine into d_out ----------------
__global__ __launch_bounds__(256) void k_gemm2(
    const ushort_t* __restrict__ yb, const ushort_t* __restrict__ w2t,
    const int* __restrict__ tok_of_slot, const float* __restrict__ slot_w,
    const int* __restrict__ offs, float* __restrict__ out)
{
  int e = blockIdx.y >> 5, mt = blockIdx.y & 31;
  int sege = offs[e + 1];
  int m0 = offs[e] + mt * 128;
  if (m0 >= sege) return;
  GEMM_PROLOGUE();
  int n0 = blockIdx.x * 128;
  int gr0 = m0 + rS; if (gr0 > 8191) gr0 = 8191;
  int gr1 = m0 + rS + 64; if (gr1 > 8191) gr1 = 8191;
  const ushort_t* a0 = yb + (size_t)gr0 * 1024 + cS;
  const ushort_t* a1 = yb + (size_t)gr1 * 1024 + cS;
  const ushort_t* b0 = w2t + (size_t)e * 2048 * 1024 + (size_t)(n0 + rS) * 1024 + cS;
  const ushort_t* b1 = b0 + (size_t)64 * 1024;
  gemm_loop(1024, a0, a1, b0, b1, ldsA, ldsB, ldsA + w * 512, ldsB + w * 512,
            ao_, bo_, acc);
#pragma unroll
  for (int fm = 0; fm < 4; fm++) {
    int row0 = m0 + wm * 64 + fm * 16 + g * 4;
    int toks[4]; float wss[4]; bool ok[4];
#pragma unroll
    for (int r = 0; r < 4; r++) {
      int rowg = row0 + r;
      ok[r] = rowg < sege;
      int rg = rowg > 8191 ? 8191 : rowg;
      toks[r] = tok_of_slot[rg];
      wss[r] = ok[r] ? slot_w[rg] : 0.f;
    }
#pragma unroll
    for (int fn = 0; fn < 4; fn++) {
      int col = n0 + wn * 64 + fn * 16 + q15;
      f32x4 v = acc[fm][fn];
#pragma unroll
      for (int r = 0; r < 4; r++)
        if (ok[r]) atomicAdd(out + (size_t)toks[r] * 2048 + col, v[r] * wss[r]);
    }
  }
}

// ---------------- launch ----------------------------------------------------
extern "C" void kernel_launch(void* const* d_in, const int* in_sizes, int n_in,
                              void* d_out, int out_size, void* d_ws, size_t ws_size,
                              hipStream_t stream)
{
  (void)in_sizes; (void)n_in; (void)out_size; (void)ws_size;
  const float* x   = (const float*)d_in[0];
  const float* w_q = (const float*)d_in[1];
  const float* w_k = (const float*)d_in[2];
  const float* w_v = (const float*)d_in[3];
  const float* w_o = (const float*)d_in[4];
  const float* anw = (const float*)d_in[5];
  const float* mnw = (const float*)d_in[6];
  const float* gw  = (const float*)d_in[7];
  const float* w1  = (const float*)d_in[8];
  const float* w3  = (const float*)d_in[9];
  const float* w2  = (const float*)d_in[10];
  float* out = (float*)d_out;

  char* ws = (char*)d_ws;
  size_t off = 0;
  auto take = [&](size_t bytes) -> void* {
    void* p = ws + off;
    off = (off + bytes + 255) & ~(size_t)255;
    return p;
  };
  ushort_t* wqkvt = (ushort_t*)take(2UL * 3072 * 2048 * 2);   // hi+lo planes
  ushort_t* wot   = (ushort_t*)take(2UL * 2048 * 2048 * 2);
  ushort_t* w13t  = (ushort_t*)take(8UL * 2048 * 2048 * 2);
  ushort_t* w2t   = (ushort_t*)take(8UL * 2048 * 1024 * 2);
  ushort_t* hbf   = (ushort_t*)take(2UL * 4096 * 2048 * 2);   // aliased as aob later
  ushort_t* qb    = (ushort_t*)take(2UL * 2 * 16 * 2048 * 128 * 2);  // aliased hmb/yb
  ushort_t* kb    = (ushort_t*)take(2UL * 2 * 4 * 2048 * 128 * 2);
  ushort_t* vtb   = (ushort_t*)take(2UL * 2 * 4 * 128 * 2048 * 2);
  float* cosT = (float*)take(2048UL * 64 * 4);
  float* sinT = (float*)take(2048UL * 64 * 4);
  int* top_idx = (int*)take(4096UL * 2 * 4);
  float* top_w = (float*)take(4096UL * 2 * 4);
  int* tok_of_slot = (int*)take(8192UL * 4);
  float* slot_w = (float*)take(8192UL * 4);
  int* cnt  = (int*)take(64);
  float* psum = (float*)take(64);
  int* offs = (int*)take(64);
  int* cur  = (int*)take(64);
  ushort_t* aob = hbf;             // hbf dead after k_gemm_qkv
  ushort_t* hmb = qb;              // qb dead after k_attn
  ushort_t* yb  = qb + 8388608;    // second half of qb region

  k_zero<<<1, 64, 0, stream>>>(cnt, psum);
  k_ropetab<<<512, 256, 0, stream>>>(cosT, sinT);
  k_transcvt2<<<dim3(64, 64, 1), 256, 0, stream>>>(w_q, wqkvt, 2048, 2048, 0, PS_WQKV);
  k_transcvt2<<<dim3(64, 16, 1), 256, 0, stream>>>(w_k, wqkvt, 2048, 512, 2048, PS_WQKV);
  k_transcvt2<<<dim3(64, 16, 1), 256, 0, stream>>>(w_v, wqkvt, 2048, 512, 2560, PS_WQKV);
  k_transcvt2<<<dim3(64, 64, 1), 256, 0, stream>>>(w_o, wot, 2048, 2048, 0, PS_WO);
  k_transcvt<<<dim3(32, 64, 8), 256, 0, stream>>>(w2, w2t, 1024, 2048, 0,
                                                  1024L * 2048, 2048L * 1024);
  k_transcvt13<<<dim3(64, 32, 8), 256, 0, stream>>>(w1, w3, w13t);
  k_rmsnorm2<<<4096, 256, 0, stream>>>(x, anw, hbf);
  k_gemm_qkv<<<dim3(24, 32, 1), 256, 0, stream>>>(hbf, wqkvt, cosT, sinT, qb, kb, vtb);
  k_attn<<<dim3(128, 16, 2), 64, 0, stream>>>(qb, kb, vtb, aob);
  k_gemm_o<<<dim3(16, 32, 1), 256, 0, stream>>>(aob, wot, x, out);
  k_rmsnorm<<<4096, 256, 0, stream>>>(out, mnw, hmb);
  k_gate<<<1024, 256, 0, stream>>>(out, gw, mnw, top_idx, top_w, cnt, psum);
  k_scan<<<1, 64, 0, stream>>>(cnt, psum, offs, cur, out + 8388608);
  k_scatter<<<16, 256, 0, stream>>>(top_idx, top_w, cur, tok_of_slot, slot_w);
  k_gemm1<<<dim3(16, 256, 1), 256, 0, stream>>>(hmb, w13t, tok_of_slot, offs, yb);
  k_gemm2<<<dim3(16, 256, 1), 256, 0, stream>>>(yb, w2t, tok_of_slot, slot_w, offs, out);
}